// Round 1
// 187.472 us; speedup vs baseline: 1.1566x; 1.1566x over previous
//
#include <hip/hip_runtime.h>

typedef __bf16 bf16x8 __attribute__((ext_vector_type(8)));
typedef float f32x4 __attribute__((ext_vector_type(4)));
typedef unsigned short u16x8 __attribute__((ext_vector_type(8)));
typedef unsigned short u16x4 __attribute__((ext_vector_type(4)));

#define MFMA16(a, b, c) __builtin_amdgcn_mfma_f32_16x16x32_bf16((a), (b), (c), 0, 0, 0)

__device__ __forceinline__ unsigned short f2bf(float f) {
  union { float f; unsigned int i; } v; v.f = f;
  unsigned int u = v.i;
  u += 0x7fffu + ((u >> 16) & 1u);   // RNE
  return (unsigned short)(u >> 16);
}

// async global->LDS, 16B per lane. LDS dest = wave-uniform base + lane*16.
__device__ __forceinline__ void gload16(const void* g, void* l) {
  __builtin_amdgcn_global_load_lds(
      (const __attribute__((address_space(1))) unsigned int*)g,
      (__attribute__((address_space(3))) unsigned int*)l, 16, 0, 0);
}

// ---------------------------------------------------------------------------
// convert_x: fp32 [4096*1024] -> bf16 (RNE). 8 elems/thread, vectorized.
// ---------------------------------------------------------------------------
__global__ __launch_bounds__(256) void convert_x(const float* __restrict__ X,
                                                 unsigned short* __restrict__ Xb) {
  size_t i = (size_t)(blockIdx.x * 256 + threadIdx.x) * 8;
  f32x4 f0 = *(const f32x4*)(X + i);
  f32x4 f1 = *(const f32x4*)(X + i + 4);
  u16x8 t;
#pragma unroll
  for (int j = 0; j < 4; ++j) { t[j] = f2bf(f0[j]); t[4 + j] = f2bf(f1[j]); }
  *(u16x8*)(Xb + i) = t;
}

// ---------------------------------------------------------------------------
// transpose_w: W [1024][N] fp32  ->  Wt [N][1024] bf16 (RNE).
// 32x32 tiles via LDS, +1 pad; coalesced reads and writes.
// ---------------------------------------------------------------------------
__global__ __launch_bounds__(256) void transpose_w(const float* __restrict__ W,
                                                   unsigned short* __restrict__ Wt,
                                                   int N) {
  __shared__ unsigned short t[32][33];
  int tx = threadIdx.x & 31, ty = threadIdx.x >> 5;   // 32 x 8
  int bx = blockIdx.x;  // tile along N
  int by = blockIdx.y;  // tile along K=1024
#pragma unroll
  for (int j = 0; j < 4; ++j) {
    int r = ty + j * 8;
    t[tx][r] = f2bf(W[(size_t)(by * 32 + r) * N + bx * 32 + tx]);
  }
  __syncthreads();
#pragma unroll
  for (int j = 0; j < 4; ++j) {
    int r = ty + j * 8;   // output row (N index)
    Wt[(size_t)(bx * 32 + r) * 1024 + by * 32 + tx] = t[r][tx];
  }
}

// ---------------------------------------------------------------------------
// m97-lineage GEMM: C[M x N] = A[M x 1024] @ Bt[N x 1024]^T + bias, fp32 acc.
// A, Bt bf16, both K-major. Tile 128x128, BK=32, 256 thr = 4 waves (2x2),
// each wave owns a 64x64 quadrant (4x4 16x16 frags, 16 MFMA/K-step).
// Staging: global_load_lds width 16 (2 issues per operand per K-step), linear
// LDS [128][32] bf16 (fragment read pattern is bank-balanced; no swizzle).
// mode 0: N=3072, scatter Q[b,h,s,d], K[b,h,s,d], V[b,h,d,s] bf16.
// mode 1: N=1024, store FP32 to OF[m*1024+n].
// C-layout: col = lane&15, row = quad*4 + r (ref-verified m92/m97 lineage).
// ---------------------------------------------------------------------------
__global__ __launch_bounds__(256) void gemm_bt(
    const unsigned short* __restrict__ A, const unsigned short* __restrict__ Bt,
    const float* __restrict__ bias,
    unsigned short* __restrict__ O0, unsigned short* __restrict__ O1,
    unsigned short* __restrict__ O2, float* __restrict__ OF, int mode) {
  __shared__ __align__(16) unsigned short As[128 * 32];
  __shared__ __align__(16) unsigned short Bs[128 * 32];

  const int K = 1024;
  int tid = threadIdx.x;
  int lane = tid & 63, wave = tid >> 6, quad = lane >> 4, l16 = lane & 15;
  int wrow = wave >> 1, wcol = wave & 1;
  int m0 = blockIdx.x * 128, n0 = blockIdx.y * 128;

  // staging chunks: c = tid + 256*i over 512 16B-chunks per operand tile.
  const unsigned short* ag[2]; const unsigned short* bg[2];
  char* al[2]; char* bl[2];
#pragma unroll
  for (int i = 0; i < 2; ++i) {
    int c = tid + 256 * i, row = c >> 2, u = c & 3;
    ag[i] = A + (size_t)(m0 + row) * K + u * 8;
    bg[i] = Bt + (size_t)(n0 + row) * K + u * 8;
    al[i] = (char*)As + c * 16;
    bl[i] = (char*)Bs + c * 16;
  }

  // fragment LDS byte offsets: row stride 64B, k-chunk = quad*16B.
  int abase = (wrow * 64 + l16) * 64 + quad * 16;   // + mt*1024
  int bbase = (wcol * 64 + l16) * 64 + quad * 16;   // + nt*1024

  f32x4 acc[4][4];
#pragma unroll
  for (int i = 0; i < 4; ++i)
#pragma unroll
    for (int j = 0; j < 4; ++j) acc[i][j] = f32x4{0.f, 0.f, 0.f, 0.f};

  for (int k0 = 0; k0 < K; k0 += 32) {
#pragma unroll
    for (int i = 0; i < 2; ++i) {
      gload16(ag[i] + k0, al[i]);
      gload16(bg[i] + k0, bl[i]);
    }
    __syncthreads();   // compiler drains vmcnt(0) before barrier
    bf16x8 af[4], bfr[4];
#pragma unroll
    for (int t = 0; t < 4; ++t) {
      af[t]  = *(const bf16x8*)((const char*)As + abase + t * 1024);
      bfr[t] = *(const bf16x8*)((const char*)Bs + bbase + t * 1024);
    }
#pragma unroll
    for (int mt = 0; mt < 4; ++mt)
#pragma unroll
      for (int nt = 0; nt < 4; ++nt)
        acc[mt][nt] = MFMA16(af[mt], bfr[nt], acc[mt][nt]);
    __syncthreads();
  }

  if (mode == 0) {
#pragma unroll
    for (int nt = 0; nt < 4; ++nt) {
      int n = n0 + wcol * 64 + nt * 16 + l16;
      float bv = bias[n];
      int seg = n >> 10, cc = n & 1023, hh = cc >> 6, d = cc & 63;
#pragma unroll
      for (int mt = 0; mt < 4; ++mt) {
        int mb = m0 + wrow * 64 + mt * 16 + quad * 4;
        int b = mb >> 11, s = mb & 2047;
        if (seg == 2) {
          u16x4 pk;
#pragma unroll
          for (int r = 0; r < 4; ++r) pk[r] = f2bf(acc[mt][nt][r] + bv);
          *(u16x4*)&O2[((size_t)((b << 4) + hh) * 64 + d) * 2048 + s] = pk;  // V[b,h,d,s]
        } else {
          unsigned short* O = seg ? O1 : O0;
#pragma unroll
          for (int r = 0; r < 4; ++r)
            O[((size_t)((b << 4) + hh) * 2048 + (s + r)) * 64 + d] = f2bf(acc[mt][nt][r] + bv);
        }
      }
    }
  } else {
#pragma unroll
    for (int nt = 0; nt < 4; ++nt) {
      int n = n0 + wcol * 64 + nt * 16 + l16;
      float bv = bias[n];
#pragma unroll
      for (int mt = 0; mt < 4; ++mt) {
        int mb = m0 + wrow * 64 + mt * 16 + quad * 4;
#pragma unroll
        for (int r = 0; r < 4; ++r)
          OF[(size_t)(mb + r) * 1024 + n] = acc[mt][nt][r] + bv;   // FP32 output
      }
    }
  }
}

// ---------------------------------------------------------------------------
// MFMA windowed flash attention (unchanged this round).
// Query i attends keys j in [i, i+255], j<S. Block = (b, h, 64-query tile);
// 4 waves; wave w owns queries [16w, 16w+16). Cross-validated vs VALU attn.
// ---------------------------------------------------------------------------
__global__ __launch_bounds__(256) void attn_kernel(
    const unsigned short* __restrict__ Q, const unsigned short* __restrict__ Kq,
    const unsigned short* __restrict__ Vt, unsigned short* __restrict__ AO) {
  __shared__ __align__(16) unsigned short Ks[32][72];      // [key][d]
  __shared__ __align__(16) unsigned short Vs[64][40];      // [d][key]
  __shared__ __align__(16) unsigned short Ps[4][16][40];   // per-wave P: [q][key]

  int bid = blockIdx.x;
  int qblk = bid & 31, h = (bid >> 5) & 15, b = bid >> 9;
  int q0 = qblk * 64;
  int tid = threadIdx.x, lane = tid & 63, wave = tid >> 6, quad = lane >> 4, l16 = lane & 15;

  const unsigned short* Qb = Q + (size_t)(((b << 4) + h) * 2048) * 64;
  const unsigned short* Kb = Kq + (size_t)(((b << 4) + h) * 2048) * 64;
  const unsigned short* Vb = Vt + (size_t)(((b << 4) + h) * 64) * 2048;

  int qrow = q0 + wave * 16 + l16;   // A-frag row m = lane&15
  bf16x8 qf0 = __builtin_bit_cast(bf16x8, *(const u16x8*)&Qb[(size_t)qrow * 64 + quad * 8]);
  bf16x8 qf1 = __builtin_bit_cast(bf16x8, *(const u16x8*)&Qb[(size_t)qrow * 64 + 32 + quad * 8]);

  float mrow[4], lrow[4];
  f32x4 zero = {0.f, 0.f, 0.f, 0.f};
  f32x4 o[4];
#pragma unroll
  for (int i = 0; i < 4; ++i) o[i] = zero;
#pragma unroll
  for (int r = 0; r < 4; ++r) { mrow[r] = -1e30f; lrow[r] = 0.f; }

  const float SCALE = 0.125f;  // 64^-0.5
  int pstart = (wave >= 2) ? 1 : 0;
  int pend = pstart + 8;

  int ki = tid >> 3, kc = (tid & 7) * 8;   // K stage: 32 keys x 64 d
  int vd = tid >> 2, vc = (tid & 3) * 8;   // V stage: 64 d x 32 keys

  for (int p = 0; p < 10; ++p) {
    int kbase = q0 + p * 32;
    {
      int s = kbase + ki; s = s > 2047 ? 2047 : s;   // clamp; masked later
      *(u16x8*)&Ks[ki][kc] = *(const u16x8*)&Kb[(size_t)s * 64 + kc];
    }
    if (kbase + vc + 7 <= 2047) {
      *(u16x8*)&Vs[vd][vc] = *(const u16x8*)&Vb[(size_t)vd * 2048 + kbase + vc];
    } else {
#pragma unroll
      for (int j = 0; j < 8; ++j) {
        int s = kbase + vc + j; s = s > 2047 ? 2047 : s;
        Vs[vd][vc + j] = Vb[(size_t)vd * 2048 + s];
      }
    }
    __syncthreads();

    if (p >= pstart && p <= pend) {
      // S = Q K^T : B-frag = K[key=lane&15][d=quad*8+j]
      f32x4 sc[2];
#pragma unroll
      for (int t = 0; t < 2; ++t) {
        bf16x8 kf0 = __builtin_bit_cast(bf16x8, *(const u16x8*)&Ks[t * 16 + l16][quad * 8]);
        bf16x8 kf1 = __builtin_bit_cast(bf16x8, *(const u16x8*)&Ks[t * 16 + l16][32 + quad * 8]);
        f32x4 z = zero;
        z = MFMA16(qf0, kf0, z);
        z = MFMA16(qf1, kf1, z);
        sc[t] = z;
      }
      float sv[2][4];
#pragma unroll
      for (int t = 0; t < 2; ++t)
#pragma unroll
        for (int r = 0; r < 4; ++r) {
          int kg = kbase + t * 16 + l16;
          int qg = q0 + wave * 16 + quad * 4 + r;
          bool valid = (kg >= qg) && (kg <= qg + 255) && (kg < 2048);
          sv[t][r] = valid ? sc[t][r] * SCALE : -1e30f;
        }
#pragma unroll
      for (int r = 0; r < 4; ++r) {
        float v = fmaxf(sv[0][r], sv[1][r]);
        v = fmaxf(v, __shfl_xor(v, 1));
        v = fmaxf(v, __shfl_xor(v, 2));
        v = fmaxf(v, __shfl_xor(v, 4));
        v = fmaxf(v, __shfl_xor(v, 8));
        float mnew = fmaxf(mrow[r], v);
        float alpha = __expf(mrow[r] - mnew);
        mrow[r] = mnew;
        float p0 = __expf(sv[0][r] - mnew);
        float p1 = __expf(sv[1][r] - mnew);
        p0 = (sv[0][r] > -5e29f) ? p0 : 0.f;
        p1 = (sv[1][r] > -5e29f) ? p1 : 0.f;
        float rs = p0 + p1;
        rs += __shfl_xor(rs, 1);
        rs += __shfl_xor(rs, 2);
        rs += __shfl_xor(rs, 4);
        rs += __shfl_xor(rs, 8);
        lrow[r] = lrow[r] * alpha + rs;
#pragma unroll
        for (int nt = 0; nt < 4; ++nt) o[nt][r] *= alpha;
        Ps[wave][quad * 4 + r][l16] = f2bf(p0);
        Ps[wave][quad * 4 + r][16 + l16] = f2bf(p1);
      }
      __threadfence_block();
      bf16x8 pf = __builtin_bit_cast(bf16x8, *(const u16x8*)&Ps[wave][l16][quad * 8]);
#pragma unroll
      for (int nt = 0; nt < 4; ++nt) {
        bf16x8 vf = __builtin_bit_cast(bf16x8, *(const u16x8*)&Vs[nt * 16 + l16][quad * 8]);
        o[nt] = MFMA16(pf, vf, o[nt]);
      }
    }
    __syncthreads();
  }

  unsigned short* dst = AO + ((size_t)(b * 2048 + q0 + wave * 16) * 1024) + h * 64;
#pragma unroll
  for (int nt = 0; nt < 4; ++nt)
#pragma unroll
    for (int r = 0; r < 4; ++r) {
      int qq = quad * 4 + r;
      dst[(size_t)qq * 1024 + nt * 16 + l16] = f2bf(o[nt][r] / lrow[r]);
    }
}

extern "C" void kernel_launch(void* const* d_in, const int* in_sizes, int n_in,
                              void* d_out, int out_size, void* d_ws, size_t ws_size,
                              hipStream_t stream) {
  const float* x = (const float*)d_in[0];
  const float* W_qkv = (const float*)d_in[1];
  const float* b_qkv = (const float*)d_in[2];
  const float* W_out = (const float*)d_in[3];
  const float* b_out = (const float*)d_in[4];
  float* out = (float*)d_out;

  // Workspace: 32 MiB total (same budget as previously-passing kernel).
  //   Qw [0,8M)  Kw [8M,16M)  Vw [16M,24M)  R3 [24M,32M)
  //   R3: W_qkv^T bf16 (6MB, dead after gemm0) then AO (8MB, written by attn).
  //   W_out^T bf16 (2MB) aliases Qw (dead after attn); x_bf16 lives in d_out
  //   (16MB fp32 buffer, only finally written by gemm1).
  unsigned short* ws = (unsigned short*)d_ws;
  unsigned short* Qw  = ws;                      // [b,h,s,d] bf16
  unsigned short* Kw  = ws + 4194304;            // [b,h,s,d] bf16
  unsigned short* Vw  = ws + 8388608;            // [b,h,d,s] bf16 (transposed)
  unsigned short* Wqt = ws + 12582912;           // [3072][1024] bf16 = W_qkv^T
  unsigned short* AO  = ws + 12582912;           // [b,s,h*64+d] bf16 (aliases Wqt)
  unsigned short* Wot = ws;                      // [1024][1024] bf16 = W_out^T (aliases Qw)
  unsigned short* Xb  = (unsigned short*)d_out;  // [4096][1024] bf16 (aliases out)

  dim3 blk(256);
  convert_x<<<dim3(2048), blk, 0, stream>>>(x, Xb);
  transpose_w<<<dim3(96, 32), blk, 0, stream>>>(W_qkv, Wqt, 3072);
  gemm_bt<<<dim3(32, 24), blk, 0, stream>>>(Xb, Wqt, b_qkv, Qw, Kw, Vw, nullptr, 0);
  attn_kernel<<<dim3(1024), blk, 0, stream>>>(Qw, Kw, Vw, AO);
  transpose_w<<<dim3(32, 32), blk, 0, stream>>>(W_out, Wot, 1024);
  gemm_bt<<<dim3(32, 8), blk, 0, stream>>>(AO, Wot, b_out, nullptr, nullptr, nullptr, out, 1);
}

// Round 2
// 176.574 us; speedup vs baseline: 1.2279x; 1.0617x over previous
//
#include <hip/hip_runtime.h>

typedef __bf16 bf16x8 __attribute__((ext_vector_type(8)));
typedef float f32x4 __attribute__((ext_vector_type(4)));
typedef unsigned short u16x8 __attribute__((ext_vector_type(8)));
typedef unsigned short u16x4 __attribute__((ext_vector_type(4)));

#define MFMA16(a, b, c) __builtin_amdgcn_mfma_f32_16x16x32_bf16((a), (b), (c), 0, 0, 0)

__device__ __forceinline__ unsigned short f2bf(float f) {
  union { float f; unsigned int i; } v; v.f = f;
  unsigned int u = v.i;
  u += 0x7fffu + ((u >> 16) & 1u);   // RNE
  return (unsigned short)(u >> 16);
}

// async global->LDS, 16B per lane. LDS dest = wave-uniform base + lane*16.
__device__ __forceinline__ void gload16(const void* g, void* l) {
  __builtin_amdgcn_global_load_lds(
      (const __attribute__((address_space(1))) unsigned int*)g,
      (__attribute__((address_space(3))) unsigned int*)l, 16, 0, 0);
}

// ---------------------------------------------------------------------------
// convert_x: fp32 [4096*1024] -> bf16 (RNE). 8 elems/thread, vectorized.
// ---------------------------------------------------------------------------
__global__ __launch_bounds__(256) void convert_x(const float* __restrict__ X,
                                                 unsigned short* __restrict__ Xb) {
  size_t i = (size_t)(blockIdx.x * 256 + threadIdx.x) * 8;
  f32x4 f0 = *(const f32x4*)(X + i);
  f32x4 f1 = *(const f32x4*)(X + i + 4);
  u16x8 t;
#pragma unroll
  for (int j = 0; j < 4; ++j) { t[j] = f2bf(f0[j]); t[4 + j] = f2bf(f1[j]); }
  *(u16x8*)(Xb + i) = t;
}

// ---------------------------------------------------------------------------
// transpose_w: W [1024][N] fp32  ->  Wt [N][1024] bf16 (RNE).
// 32x32 tiles via LDS, +1 pad; coalesced reads and writes.
// ---------------------------------------------------------------------------
__global__ __launch_bounds__(256) void transpose_w(const float* __restrict__ W,
                                                   unsigned short* __restrict__ Wt,
                                                   int N) {
  __shared__ unsigned short t[32][33];
  int tx = threadIdx.x & 31, ty = threadIdx.x >> 5;   // 32 x 8
  int bx = blockIdx.x;  // tile along N
  int by = blockIdx.y;  // tile along K=1024
#pragma unroll
  for (int j = 0; j < 4; ++j) {
    int r = ty + j * 8;
    t[tx][r] = f2bf(W[(size_t)(by * 32 + r) * N + bx * 32 + tx]);
  }
  __syncthreads();
#pragma unroll
  for (int j = 0; j < 4; ++j) {
    int r = ty + j * 8;   // output row (N index)
    Wt[(size_t)(bx * 32 + r) * 1024 + by * 32 + tx] = t[r][tx];
  }
}

// ---------------------------------------------------------------------------
// m97-lineage GEMM + T3/T4 counted-vmcnt double-buffer pipeline + T1 swizzle.
// C[M x N] = A[M x 1024] @ Bt[N x 1024]^T + bias, fp32 acc.
// A, Bt bf16, both K-major. Tile 128x128, BK=32, 256 thr = 4 waves (2x2),
// each wave owns a 64x64 quadrant (4x4 16x16 frags, 16 MFMA/K-step).
// K-loop: raw s_barrier + asm s_waitcnt; NO __syncthreads (its vmcnt(0)
// drain is the ~70% stall seen in round 1). Per half-step:
//   STAGE(tile t+1 -> other buf);          // 4x global_load_lds stay in flight
//   s_waitcnt vmcnt(4);                    // waits ONLY tile t (issued 1 iter ago)
//   s_barrier;                             // tile t visible to all waves
//   ds_read + 16 MFMA;                     // compiler inserts lgkm waits for MFMA
//   s_waitcnt lgkmcnt(0); s_barrier;       // all reads retired before buf reuse
// mode 0: N=3072, scatter Q[b,h,s,d], K[b,h,s,d], V[b,h,d,s] bf16.
// mode 1: N=1024, store FP32 to OF[m*1024+n].
// C-layout: col = lane&15, row = quad*4 + r (ref-verified m92/m97 lineage).
// ---------------------------------------------------------------------------
__global__ __launch_bounds__(256) void gemm_bt(
    const unsigned short* __restrict__ A, const unsigned short* __restrict__ Bt,
    const float* __restrict__ bias,
    unsigned short* __restrict__ O0, unsigned short* __restrict__ O1,
    unsigned short* __restrict__ O2, float* __restrict__ OF, int mode) {
  __shared__ __align__(16) unsigned short As0[128 * 32];
  __shared__ __align__(16) unsigned short Bs0[128 * 32];
  __shared__ __align__(16) unsigned short As1[128 * 32];
  __shared__ __align__(16) unsigned short Bs1[128 * 32];

  const int K = 1024;
  int tid = threadIdx.x;
  int lane = tid & 63, wave = tid >> 6, quad = lane >> 4, l16 = lane & 15;
  int wrow = wave >> 1, wcol = wave & 1;

  // T1: XCD-aware bijective swizzle (nwg divisible by 8 for both modes).
  int gx = gridDim.x;
  int nwg = gx * gridDim.y;
  int lin = blockIdx.y * gx + blockIdx.x;
  int swz = (lin & 7) * (nwg >> 3) + (lin >> 3);
  int m0 = (swz % gx) * 128, n0 = (swz / gx) * 128;

  // staging chunks: c = tid + 256*i over 512 16B-chunks per operand tile.
  const unsigned short* ag[2]; const unsigned short* bg[2];
  int loff[2];
#pragma unroll
  for (int i = 0; i < 2; ++i) {
    int c = tid + 256 * i, row = c >> 2, u = c & 3;
    ag[i] = A + (size_t)(m0 + row) * K + u * 8;
    bg[i] = Bt + (size_t)(n0 + row) * K + u * 8;
    loff[i] = c * 16;
  }

  // fragment LDS byte offsets: row stride 64B, k-chunk = quad*16B.
  int abase = (wrow * 64 + l16) * 64 + quad * 16;   // + mt*1024
  int bbase = (wcol * 64 + l16) * 64 + quad * 16;   // + nt*1024

  f32x4 acc[4][4];
#pragma unroll
  for (int i = 0; i < 4; ++i)
#pragma unroll
    for (int j = 0; j < 4; ++j) acc[i][j] = f32x4{0.f, 0.f, 0.f, 0.f};

  auto STAGE = [&](int k0, char* Asb, char* Bsb) {
#pragma unroll
    for (int i = 0; i < 2; ++i) {
      gload16(ag[i] + k0, Asb + loff[i]);
      gload16(bg[i] + k0, Bsb + loff[i]);
    }
  };
  auto COMPUTE = [&](const char* Asb, const char* Bsb) {
    bf16x8 af[4], bfr[4];
#pragma unroll
    for (int t = 0; t < 4; ++t) {
      af[t]  = *(const bf16x8*)(Asb + abase + t * 1024);
      bfr[t] = *(const bf16x8*)(Bsb + bbase + t * 1024);
    }
#pragma unroll
    for (int mt = 0; mt < 4; ++mt)
#pragma unroll
      for (int nt = 0; nt < 4; ++nt)
        acc[mt][nt] = MFMA16(af[mt], bfr[nt], acc[mt][nt]);
  };
#define WAIT_VM4  asm volatile("s_waitcnt vmcnt(4)" ::: "memory")
#define WAIT_VM0  asm volatile("s_waitcnt vmcnt(0)" ::: "memory")
#define WAIT_LGKM asm volatile("s_waitcnt lgkmcnt(0)" ::: "memory")
#define BAR       __builtin_amdgcn_s_barrier()

  STAGE(0, (char*)As0, (char*)Bs0);               // prologue: tile 0 in flight
  for (int t = 0; t < 30; t += 2) {
    STAGE((t + 1) * 32, (char*)As1, (char*)Bs1);  // tile t+1 -> buf1
    WAIT_VM4; BAR;                                // tile t landed
    COMPUTE((const char*)As0, (const char*)Bs0);
    WAIT_LGKM; BAR;                               // buf0 free for reuse
    STAGE((t + 2) * 32, (char*)As0, (char*)Bs0);  // tile t+2 -> buf0
    WAIT_VM4; BAR;                                // tile t+1 landed
    COMPUTE((const char*)As1, (const char*)Bs1);
    WAIT_LGKM; BAR;                               // buf1 free for reuse
  }
  STAGE(31 * 32, (char*)As1, (char*)Bs1);         // last tile -> buf1
  WAIT_VM4; BAR;
  COMPUTE((const char*)As0, (const char*)Bs0);
  WAIT_LGKM; BAR;
  WAIT_VM0; BAR;                                  // drain last tile
  COMPUTE((const char*)As1, (const char*)Bs1);

  if (mode == 0) {
#pragma unroll
    for (int nt = 0; nt < 4; ++nt) {
      int n = n0 + wcol * 64 + nt * 16 + l16;
      float bv = bias[n];
      int seg = n >> 10, cc = n & 1023, hh = cc >> 6, d = cc & 63;
#pragma unroll
      for (int mt = 0; mt < 4; ++mt) {
        int mb = m0 + wrow * 64 + mt * 16 + quad * 4;
        int b = mb >> 11, s = mb & 2047;
        if (seg == 2) {
          u16x4 pk;
#pragma unroll
          for (int r = 0; r < 4; ++r) pk[r] = f2bf(acc[mt][nt][r] + bv);
          *(u16x4*)&O2[((size_t)((b << 4) + hh) * 64 + d) * 2048 + s] = pk;  // V[b,h,d,s]
        } else {
          unsigned short* O = seg ? O1 : O0;
#pragma unroll
          for (int r = 0; r < 4; ++r)
            O[((size_t)((b << 4) + hh) * 2048 + (s + r)) * 64 + d] = f2bf(acc[mt][nt][r] + bv);
        }
      }
    }
  } else {
#pragma unroll
    for (int nt = 0; nt < 4; ++nt) {
      int n = n0 + wcol * 64 + nt * 16 + l16;
      float bv = bias[n];
#pragma unroll
      for (int mt = 0; mt < 4; ++mt) {
        int mb = m0 + wrow * 64 + mt * 16 + quad * 4;
#pragma unroll
        for (int r = 0; r < 4; ++r)
          OF[(size_t)(mb + r) * 1024 + n] = acc[mt][nt][r] + bv;   // FP32 output
      }
    }
  }
}

// ---------------------------------------------------------------------------
// MFMA windowed flash attention (unchanged this round).
// Query i attends keys j in [i, i+255], j<S. Block = (b, h, 64-query tile);
// 4 waves; wave w owns queries [16w, 16w+16). Cross-validated vs VALU attn.
// ---------------------------------------------------------------------------
__global__ __launch_bounds__(256) void attn_kernel(
    const unsigned short* __restrict__ Q, const unsigned short* __restrict__ Kq,
    const unsigned short* __restrict__ Vt, unsigned short* __restrict__ AO) {
  __shared__ __align__(16) unsigned short Ks[32][72];      // [key][d]
  __shared__ __align__(16) unsigned short Vs[64][40];      // [d][key]
  __shared__ __align__(16) unsigned short Ps[4][16][40];   // per-wave P: [q][key]

  int bid = blockIdx.x;
  int qblk = bid & 31, h = (bid >> 5) & 15, b = bid >> 9;
  int q0 = qblk * 64;
  int tid = threadIdx.x, lane = tid & 63, wave = tid >> 6, quad = lane >> 4, l16 = lane & 15;

  const unsigned short* Qb = Q + (size_t)(((b << 4) + h) * 2048) * 64;
  const unsigned short* Kb = Kq + (size_t)(((b << 4) + h) * 2048) * 64;
  const unsigned short* Vb = Vt + (size_t)(((b << 4) + h) * 64) * 2048;

  int qrow = q0 + wave * 16 + l16;   // A-frag row m = lane&15
  bf16x8 qf0 = __builtin_bit_cast(bf16x8, *(const u16x8*)&Qb[(size_t)qrow * 64 + quad * 8]);
  bf16x8 qf1 = __builtin_bit_cast(bf16x8, *(const u16x8*)&Qb[(size_t)qrow * 64 + 32 + quad * 8]);

  float mrow[4], lrow[4];
  f32x4 zero = {0.f, 0.f, 0.f, 0.f};
  f32x4 o[4];
#pragma unroll
  for (int i = 0; i < 4; ++i) o[i] = zero;
#pragma unroll
  for (int r = 0; r < 4; ++r) { mrow[r] = -1e30f; lrow[r] = 0.f; }

  const float SCALE = 0.125f;  // 64^-0.5
  int pstart = (wave >= 2) ? 1 : 0;
  int pend = pstart + 8;

  int ki = tid >> 3, kc = (tid & 7) * 8;   // K stage: 32 keys x 64 d
  int vd = tid >> 2, vc = (tid & 3) * 8;   // V stage: 64 d x 32 keys

  for (int p = 0; p < 10; ++p) {
    int kbase = q0 + p * 32;
    {
      int s = kbase + ki; s = s > 2047 ? 2047 : s;   // clamp; masked later
      *(u16x8*)&Ks[ki][kc] = *(const u16x8*)&Kb[(size_t)s * 64 + kc];
    }
    if (kbase + vc + 7 <= 2047) {
      *(u16x8*)&Vs[vd][vc] = *(const u16x8*)&Vb[(size_t)vd * 2048 + kbase + vc];
    } else {
#pragma unroll
      for (int j = 0; j < 8; ++j) {
        int s = kbase + vc + j; s = s > 2047 ? 2047 : s;
        Vs[vd][vc + j] = Vb[(size_t)vd * 2048 + s];
      }
    }
    __syncthreads();

    if (p >= pstart && p <= pend) {
      // S = Q K^T : B-frag = K[key=lane&15][d=quad*8+j]
      f32x4 sc[2];
#pragma unroll
      for (int t = 0; t < 2; ++t) {
        bf16x8 kf0 = __builtin_bit_cast(bf16x8, *(const u16x8*)&Ks[t * 16 + l16][quad * 8]);
        bf16x8 kf1 = __builtin_bit_cast(bf16x8, *(const u16x8*)&Ks[t * 16 + l16][32 + quad * 8]);
        f32x4 z = zero;
        z = MFMA16(qf0, kf0, z);
        z = MFMA16(qf1, kf1, z);
        sc[t] = z;
      }
      float sv[2][4];
#pragma unroll
      for (int t = 0; t < 2; ++t)
#pragma unroll
        for (int r = 0; r < 4; ++r) {
          int kg = kbase + t * 16 + l16;
          int qg = q0 + wave * 16 + quad * 4 + r;
          bool valid = (kg >= qg) && (kg <= qg + 255) && (kg < 2048);
          sv[t][r] = valid ? sc[t][r] * SCALE : -1e30f;
        }
#pragma unroll
      for (int r = 0; r < 4; ++r) {
        float v = fmaxf(sv[0][r], sv[1][r]);
        v = fmaxf(v, __shfl_xor(v, 1));
        v = fmaxf(v, __shfl_xor(v, 2));
        v = fmaxf(v, __shfl_xor(v, 4));
        v = fmaxf(v, __shfl_xor(v, 8));
        float mnew = fmaxf(mrow[r], v);
        float alpha = __expf(mrow[r] - mnew);
        mrow[r] = mnew;
        float p0 = __expf(sv[0][r] - mnew);
        float p1 = __expf(sv[1][r] - mnew);
        p0 = (sv[0][r] > -5e29f) ? p0 : 0.f;
        p1 = (sv[1][r] > -5e29f) ? p1 : 0.f;
        float rs = p0 + p1;
        rs += __shfl_xor(rs, 1);
        rs += __shfl_xor(rs, 2);
        rs += __shfl_xor(rs, 4);
        rs += __shfl_xor(rs, 8);
        lrow[r] = lrow[r] * alpha + rs;
#pragma unroll
        for (int nt = 0; nt < 4; ++nt) o[nt][r] *= alpha;
        Ps[wave][quad * 4 + r][l16] = f2bf(p0);
        Ps[wave][quad * 4 + r][16 + l16] = f2bf(p1);
      }
      __threadfence_block();
      bf16x8 pf = __builtin_bit_cast(bf16x8, *(const u16x8*)&Ps[wave][l16][quad * 8]);
#pragma unroll
      for (int nt = 0; nt < 4; ++nt) {
        bf16x8 vf = __builtin_bit_cast(bf16x8, *(const u16x8*)&Vs[nt * 16 + l16][quad * 8]);
        o[nt] = MFMA16(pf, vf, o[nt]);
      }
    }
    __syncthreads();
  }

  unsigned short* dst = AO + ((size_t)(b * 2048 + q0 + wave * 16) * 1024) + h * 64;
#pragma unroll
  for (int nt = 0; nt < 4; ++nt)
#pragma unroll
    for (int r = 0; r < 4; ++r) {
      int qq = quad * 4 + r;
      dst[(size_t)qq * 1024 + nt * 16 + l16] = f2bf(o[nt][r] / lrow[r]);
    }
}

extern "C" void kernel_launch(void* const* d_in, const int* in_sizes, int n_in,
                              void* d_out, int out_size, void* d_ws, size_t ws_size,
                              hipStream_t stream) {
  const float* x = (const float*)d_in[0];
  const float* W_qkv = (const float*)d_in[1];
  const float* b_qkv = (const float*)d_in[2];
  const float* W_out = (const float*)d_in[3];
  const float* b_out = (const float*)d_in[4];
  float* out = (float*)d_out;

  // Workspace: 32 MiB total.
  //   Qw [0,8M)  Kw [8M,16M)  Vw [16M,24M)  R3 [24M,32M)
  //   R3: W_qkv^T bf16 (6MB, dead after gemm0) then AO (8MB, written by attn).
  //   W_out^T bf16 (2MB) aliases Qw (dead after attn); x_bf16 lives in d_out
  //   (16MB fp32 buffer, only finally written by gemm1).
  unsigned short* ws = (unsigned short*)d_ws;
  unsigned short* Qw  = ws;                      // [b,h,s,d] bf16
  unsigned short* Kw  = ws + 4194304;            // [b,h,s,d] bf16
  unsigned short* Vw  = ws + 8388608;            // [b,h,d,s] bf16 (transposed)
  unsigned short* Wqt = ws + 12582912;           // [3072][1024] bf16 = W_qkv^T
  unsigned short* AO  = ws + 12582912;           // [b,s,h*64+d] bf16 (aliases Wqt)
  unsigned short* Wot = ws;                      // [1024][1024] bf16 = W_out^T (aliases Qw)
  unsigned short* Xb  = (unsigned short*)d_out;  // [4096][1024] bf16 (aliases out)

  dim3 blk(256);
  convert_x<<<dim3(2048), blk, 0, stream>>>(x, Xb);
  transpose_w<<<dim3(96, 32), blk, 0, stream>>>(W_qkv, Wqt, 3072);
  gemm_bt<<<dim3(32, 24), blk, 0, stream>>>(Xb, Wqt, b_qkv, Qw, Kw, Vw, nullptr, 0);
  attn_kernel<<<dim3(1024), blk, 0, stream>>>(Qw, Kw, Vw, AO);
  transpose_w<<<dim3(32, 32), blk, 0, stream>>>(W_out, Wot, 1024);
  gemm_bt<<<dim3(32, 8), blk, 0, stream>>>(AO, Wot, b_out, nullptr, nullptr, nullptr, out, 1);
}

// Round 3
// 170.198 us; speedup vs baseline: 1.2739x; 1.0375x over previous
//
#include <hip/hip_runtime.h>

typedef __bf16 bf16x8 __attribute__((ext_vector_type(8)));
typedef float f32x4 __attribute__((ext_vector_type(4)));
typedef unsigned short u16x8 __attribute__((ext_vector_type(8)));
typedef unsigned short u16x4 __attribute__((ext_vector_type(4)));

#define MFMA16(a, b, c) __builtin_amdgcn_mfma_f32_16x16x32_bf16((a), (b), (c), 0, 0, 0)

__device__ __forceinline__ unsigned short f2bf(float f) {
  union { float f; unsigned int i; } v; v.f = f;
  unsigned int u = v.i;
  u += 0x7fffu + ((u >> 16) & 1u);   // RNE
  return (unsigned short)(u >> 16);
}

// async global->LDS, 16B per lane. LDS dest = wave-uniform base + lane*16.
__device__ __forceinline__ void gload16(const void* g, void* l) {
  __builtin_amdgcn_global_load_lds(
      (const __attribute__((address_space(1))) unsigned int*)g,
      (__attribute__((address_space(3))) unsigned int*)l, 16, 0, 0);
}

// ---------------------------------------------------------------------------
// convert_x: fp32 [4096*1024] -> bf16 (RNE). 8 elems/thread, vectorized.
// ---------------------------------------------------------------------------
__global__ __launch_bounds__(256) void convert_x(const float* __restrict__ X,
                                                 unsigned short* __restrict__ Xb) {
  size_t i = (size_t)(blockIdx.x * 256 + threadIdx.x) * 8;
  f32x4 f0 = *(const f32x4*)(X + i);
  f32x4 f1 = *(const f32x4*)(X + i + 4);
  u16x8 t;
#pragma unroll
  for (int j = 0; j < 4; ++j) { t[j] = f2bf(f0[j]); t[4 + j] = f2bf(f1[j]); }
  *(u16x8*)(Xb + i) = t;
}

// ---------------------------------------------------------------------------
// transpose_w: W [1024][N] fp32  ->  Wt [N][1024] bf16 (RNE).
// 32x32 tiles via LDS, +1 pad; coalesced reads and writes.
// ---------------------------------------------------------------------------
__global__ __launch_bounds__(256) void transpose_w(const float* __restrict__ W,
                                                   unsigned short* __restrict__ Wt,
                                                   int N) {
  __shared__ unsigned short t[32][33];
  int tx = threadIdx.x & 31, ty = threadIdx.x >> 5;   // 32 x 8
  int bx = blockIdx.x;  // tile along N
  int by = blockIdx.y;  // tile along K=1024
#pragma unroll
  for (int j = 0; j < 4; ++j) {
    int r = ty + j * 8;
    t[tx][r] = f2bf(W[(size_t)(by * 32 + r) * N + bx * 32 + tx]);
  }
  __syncthreads();
#pragma unroll
  for (int j = 0; j < 4; ++j) {
    int r = ty + j * 8;   // output row (N index)
    Wt[(size_t)(bx * 32 + r) * 1024 + by * 32 + tx] = t[r][tx];
  }
}

// ---------------------------------------------------------------------------
// m97-lineage GEMM, 8-wave variant + T4 counted-vmcnt double buffer.
// C[M x N] = A[M x 1024] @ Bt[N x 1024]^T + bias, fp32 acc.
// A, Bt bf16, both K-major. Tile 128x128, BK=32, 512 thr = 8 waves (2M x 4N):
// wave w (wr=w>>2, wc=w&3) owns a 64x32 sub-tile: 4x2 16x16 frags,
// 8 MFMA/K-step. Staging: each thread issues exactly one 16B A-chunk and one
// B-chunk via global_load_lds; linear LDS [128][32] bf16 (bank-balanced for
// the 64B-row-stride b128 fragment reads; no swizzle needed).
// K-loop (counted vmcnt, raw barriers, no __syncthreads vmcnt(0) drain):
//   STAGE(t+1 -> other buf);            // 2 loads/thread stay in flight
//   s_waitcnt vmcnt(2);                 // waits ONLY tile t (issued 1 iter ago)
//   s_barrier;  ds_read + 8 MFMA;
//   s_waitcnt lgkmcnt(0); s_barrier;    // all reads retired before buf reuse
// NO XCD swizzle: round-2 A/B showed it doubles FETCH_SIZE (L2 locality loss).
// mode 0: N=3072, scatter Q[b,h,s,d], K[b,h,s,d], V[b,h,d,s] bf16.
// mode 1: N=1024, store FP32 to OF[m*1024+n].
// C-layout: col = lane&15, row = quad*4 + r (ref-verified m92/m97 lineage).
// ---------------------------------------------------------------------------
__global__ __launch_bounds__(512) void gemm_bt(
    const unsigned short* __restrict__ A, const unsigned short* __restrict__ Bt,
    const float* __restrict__ bias,
    unsigned short* __restrict__ O0, unsigned short* __restrict__ O1,
    unsigned short* __restrict__ O2, float* __restrict__ OF, int mode) {
  __shared__ __align__(16) unsigned short As0[128 * 32];
  __shared__ __align__(16) unsigned short Bs0[128 * 32];
  __shared__ __align__(16) unsigned short As1[128 * 32];
  __shared__ __align__(16) unsigned short Bs1[128 * 32];

  const int K = 1024;
  int tid = threadIdx.x;
  int lane = tid & 63, wave = tid >> 6, quad = lane >> 4, l16 = lane & 15;
  int wr = wave >> 2, wc = wave & 3;
  int m0 = blockIdx.x * 128, n0 = blockIdx.y * 128;

  // staging: thread tid owns 16B chunk tid of each operand tile.
  // chunk c: row = c>>2, 16B-unit u = c&3. LDS byte offset = c*16 (linear).
  int srow = tid >> 2, su = tid & 3;
  const unsigned short* ag = A + (size_t)(m0 + srow) * K + su * 8;
  const unsigned short* bg = Bt + (size_t)(n0 + srow) * K + su * 8;
  int loff = tid * 16;

  // fragment LDS byte offsets: row stride 64B, k-chunk = quad*16B.
  int abase = (wr * 64 + l16) * 64 + quad * 16;   // + mt*1024, mt 0..3
  int bbase = (wc * 32 + l16) * 64 + quad * 16;   // + nt*1024, nt 0..1

  f32x4 acc[4][2];
#pragma unroll
  for (int i = 0; i < 4; ++i)
#pragma unroll
    for (int j = 0; j < 2; ++j) acc[i][j] = f32x4{0.f, 0.f, 0.f, 0.f};

  auto STAGE = [&](int k0, char* Asb, char* Bsb) {
    gload16(ag + k0, Asb + loff);
    gload16(bg + k0, Bsb + loff);
  };
  auto COMPUTE = [&](const char* Asb, const char* Bsb) {
    bf16x8 af[4], bfr[2];
#pragma unroll
    for (int t = 0; t < 4; ++t)
      af[t] = *(const bf16x8*)(Asb + abase + t * 1024);
#pragma unroll
    for (int t = 0; t < 2; ++t)
      bfr[t] = *(const bf16x8*)(Bsb + bbase + t * 1024);
#pragma unroll
    for (int mt = 0; mt < 4; ++mt)
#pragma unroll
      for (int nt = 0; nt < 2; ++nt)
        acc[mt][nt] = MFMA16(af[mt], bfr[nt], acc[mt][nt]);
  };
#define WAIT_VM2  asm volatile("s_waitcnt vmcnt(2)" ::: "memory")
#define WAIT_VM0  asm volatile("s_waitcnt vmcnt(0)" ::: "memory")
#define WAIT_LGKM asm volatile("s_waitcnt lgkmcnt(0)" ::: "memory")
#define BAR       __builtin_amdgcn_s_barrier()

  STAGE(0, (char*)As0, (char*)Bs0);               // prologue: tile 0 in flight
  for (int t = 0; t < 30; t += 2) {
    STAGE((t + 1) * 32, (char*)As1, (char*)Bs1);  // tile t+1 -> buf1
    WAIT_VM2; BAR;                                // tile t landed
    COMPUTE((const char*)As0, (const char*)Bs0);
    WAIT_LGKM; BAR;                               // buf0 free for reuse
    STAGE((t + 2) * 32, (char*)As0, (char*)Bs0);  // tile t+2 -> buf0
    WAIT_VM2; BAR;                                // tile t+1 landed
    COMPUTE((const char*)As1, (const char*)Bs1);
    WAIT_LGKM; BAR;                               // buf1 free for reuse
  }
  STAGE(31 * 32, (char*)As1, (char*)Bs1);         // last tile -> buf1
  WAIT_VM2; BAR;
  COMPUTE((const char*)As0, (const char*)Bs0);
  WAIT_LGKM; BAR;
  WAIT_VM0; BAR;                                  // drain last tile
  COMPUTE((const char*)As1, (const char*)Bs1);

  if (mode == 0) {
#pragma unroll
    for (int nt = 0; nt < 2; ++nt) {
      int n = n0 + wc * 32 + nt * 16 + l16;
      float bv = bias[n];
      int seg = n >> 10, cc = n & 1023, hh = cc >> 6, d = cc & 63;
#pragma unroll
      for (int mt = 0; mt < 4; ++mt) {
        int mb = m0 + wr * 64 + mt * 16 + quad * 4;
        int b = mb >> 11, s = mb & 2047;
        if (seg == 2) {
          u16x4 pk;
#pragma unroll
          for (int r = 0; r < 4; ++r) pk[r] = f2bf(acc[mt][nt][r] + bv);
          *(u16x4*)&O2[((size_t)((b << 4) + hh) * 64 + d) * 2048 + s] = pk;  // V[b,h,d,s]
        } else {
          unsigned short* O = seg ? O1 : O0;
#pragma unroll
          for (int r = 0; r < 4; ++r)
            O[((size_t)((b << 4) + hh) * 2048 + (s + r)) * 64 + d] = f2bf(acc[mt][nt][r] + bv);
        }
      }
    }
  } else {
#pragma unroll
    for (int nt = 0; nt < 2; ++nt) {
      int n = n0 + wc * 32 + nt * 16 + l16;
      float bv = bias[n];
#pragma unroll
      for (int mt = 0; mt < 4; ++mt) {
        int mb = m0 + wr * 64 + mt * 16 + quad * 4;
#pragma unroll
        for (int r = 0; r < 4; ++r)
          OF[(size_t)(mb + r) * 1024 + n] = acc[mt][nt][r] + bv;   // FP32 output
      }
    }
  }
}

// ---------------------------------------------------------------------------
// MFMA windowed flash attention (unchanged this round).
// Query i attends keys j in [i, i+255], j<S. Block = (b, h, 64-query tile);
// 4 waves; wave w owns queries [16w, 16w+16). Cross-validated vs VALU attn.
// ---------------------------------------------------------------------------
__global__ __launch_bounds__(256) void attn_kernel(
    const unsigned short* __restrict__ Q, const unsigned short* __restrict__ Kq,
    const unsigned short* __restrict__ Vt, unsigned short* __restrict__ AO) {
  __shared__ __align__(16) unsigned short Ks[32][72];      // [key][d]
  __shared__ __align__(16) unsigned short Vs[64][40];      // [d][key]
  __shared__ __align__(16) unsigned short Ps[4][16][40];   // per-wave P: [q][key]

  int bid = blockIdx.x;
  int qblk = bid & 31, h = (bid >> 5) & 15, b = bid >> 9;
  int q0 = qblk * 64;
  int tid = threadIdx.x, lane = tid & 63, wave = tid >> 6, quad = lane >> 4, l16 = lane & 15;

  const unsigned short* Qb = Q + (size_t)(((b << 4) + h) * 2048) * 64;
  const unsigned short* Kb = Kq + (size_t)(((b << 4) + h) * 2048) * 64;
  const unsigned short* Vb = Vt + (size_t)(((b << 4) + h) * 64) * 2048;

  int qrow = q0 + wave * 16 + l16;   // A-frag row m = lane&15
  bf16x8 qf0 = __builtin_bit_cast(bf16x8, *(const u16x8*)&Qb[(size_t)qrow * 64 + quad * 8]);
  bf16x8 qf1 = __builtin_bit_cast(bf16x8, *(const u16x8*)&Qb[(size_t)qrow * 64 + 32 + quad * 8]);

  float mrow[4], lrow[4];
  f32x4 zero = {0.f, 0.f, 0.f, 0.f};
  f32x4 o[4];
#pragma unroll
  for (int i = 0; i < 4; ++i) o[i] = zero;
#pragma unroll
  for (int r = 0; r < 4; ++r) { mrow[r] = -1e30f; lrow[r] = 0.f; }

  const float SCALE = 0.125f;  // 64^-0.5
  int pstart = (wave >= 2) ? 1 : 0;
  int pend = pstart + 8;

  int ki = tid >> 3, kc = (tid & 7) * 8;   // K stage: 32 keys x 64 d
  int vd = tid >> 2, vc = (tid & 3) * 8;   // V stage: 64 d x 32 keys

  for (int p = 0; p < 10; ++p) {
    int kbase = q0 + p * 32;
    {
      int s = kbase + ki; s = s > 2047 ? 2047 : s;   // clamp; masked later
      *(u16x8*)&Ks[ki][kc] = *(const u16x8*)&Kb[(size_t)s * 64 + kc];
    }
    if (kbase + vc + 7 <= 2047) {
      *(u16x8*)&Vs[vd][vc] = *(const u16x8*)&Vb[(size_t)vd * 2048 + kbase + vc];
    } else {
#pragma unroll
      for (int j = 0; j < 8; ++j) {
        int s = kbase + vc + j; s = s > 2047 ? 2047 : s;
        Vs[vd][vc + j] = Vb[(size_t)vd * 2048 + s];
      }
    }
    __syncthreads();

    if (p >= pstart && p <= pend) {
      // S = Q K^T : B-frag = K[key=lane&15][d=quad*8+j]
      f32x4 sc[2];
#pragma unroll
      for (int t = 0; t < 2; ++t) {
        bf16x8 kf0 = __builtin_bit_cast(bf16x8, *(const u16x8*)&Ks[t * 16 + l16][quad * 8]);
        bf16x8 kf1 = __builtin_bit_cast(bf16x8, *(const u16x8*)&Ks[t * 16 + l16][32 + quad * 8]);
        f32x4 z = zero;
        z = MFMA16(qf0, kf0, z);
        z = MFMA16(qf1, kf1, z);
        sc[t] = z;
      }
      float sv[2][4];
#pragma unroll
      for (int t = 0; t < 2; ++t)
#pragma unroll
        for (int r = 0; r < 4; ++r) {
          int kg = kbase + t * 16 + l16;
          int qg = q0 + wave * 16 + quad * 4 + r;
          bool valid = (kg >= qg) && (kg <= qg + 255) && (kg < 2048);
          sv[t][r] = valid ? sc[t][r] * SCALE : -1e30f;
        }
#pragma unroll
      for (int r = 0; r < 4; ++r) {
        float v = fmaxf(sv[0][r], sv[1][r]);
        v = fmaxf(v, __shfl_xor(v, 1));
        v = fmaxf(v, __shfl_xor(v, 2));
        v = fmaxf(v, __shfl_xor(v, 4));
        v = fmaxf(v, __shfl_xor(v, 8));
        float mnew = fmaxf(mrow[r], v);
        float alpha = __expf(mrow[r] - mnew);
        mrow[r] = mnew;
        float p0 = __expf(sv[0][r] - mnew);
        float p1 = __expf(sv[1][r] - mnew);
        p0 = (sv[0][r] > -5e29f) ? p0 : 0.f;
        p1 = (sv[1][r] > -5e29f) ? p1 : 0.f;
        float rs = p0 + p1;
        rs += __shfl_xor(rs, 1);
        rs += __shfl_xor(rs, 2);
        rs += __shfl_xor(rs, 4);
        rs += __shfl_xor(rs, 8);
        lrow[r] = lrow[r] * alpha + rs;
#pragma unroll
        for (int nt = 0; nt < 4; ++nt) o[nt][r] *= alpha;
        Ps[wave][quad * 4 + r][l16] = f2bf(p0);
        Ps[wave][quad * 4 + r][16 + l16] = f2bf(p1);
      }
      __threadfence_block();
      bf16x8 pf = __builtin_bit_cast(bf16x8, *(const u16x8*)&Ps[wave][l16][quad * 8]);
#pragma unroll
      for (int nt = 0; nt < 4; ++nt) {
        bf16x8 vf = __builtin_bit_cast(bf16x8, *(const u16x8*)&Vs[nt * 16 + l16][quad * 8]);
        o[nt] = MFMA16(pf, vf, o[nt]);
      }
    }
    __syncthreads();
  }

  unsigned short* dst = AO + ((size_t)(b * 2048 + q0 + wave * 16) * 1024) + h * 64;
#pragma unroll
  for (int nt = 0; nt < 4; ++nt)
#pragma unroll
    for (int r = 0; r < 4; ++r) {
      int qq = quad * 4 + r;
      dst[(size_t)qq * 1024 + nt * 16 + l16] = f2bf(o[nt][r] / lrow[r]);
    }
}

extern "C" void kernel_launch(void* const* d_in, const int* in_sizes, int n_in,
                              void* d_out, int out_size, void* d_ws, size_t ws_size,
                              hipStream_t stream) {
  const float* x = (const float*)d_in[0];
  const float* W_qkv = (const float*)d_in[1];
  const float* b_qkv = (const float*)d_in[2];
  const float* W_out = (const float*)d_in[3];
  const float* b_out = (const float*)d_in[4];
  float* out = (float*)d_out;

  // Workspace: 32 MiB total.
  //   Qw [0,8M)  Kw [8M,16M)  Vw [16M,24M)  R3 [24M,32M)
  //   R3: W_qkv^T bf16 (6MB, dead after gemm0) then AO (8MB, written by attn).
  //   W_out^T bf16 (2MB) aliases Qw (dead after attn); x_bf16 lives in d_out
  //   (16MB fp32 buffer, only finally written by gemm1).
  unsigned short* ws = (unsigned short*)d_ws;
  unsigned short* Qw  = ws;                      // [b,h,s,d] bf16
  unsigned short* Kw  = ws + 4194304;            // [b,h,s,d] bf16
  unsigned short* Vw  = ws + 8388608;            // [b,h,d,s] bf16 (transposed)
  unsigned short* Wqt = ws + 12582912;           // [3072][1024] bf16 = W_qkv^T
  unsigned short* AO  = ws + 12582912;           // [b,s,h*64+d] bf16 (aliases Wqt)
  unsigned short* Wot = ws;                      // [1024][1024] bf16 = W_out^T (aliases Qw)
  unsigned short* Xb  = (unsigned short*)d_out;  // [4096][1024] bf16 (aliases out)

  dim3 blk(256);
  dim3 gblk(512);
  convert_x<<<dim3(2048), blk, 0, stream>>>(x, Xb);
  transpose_w<<<dim3(96, 32), blk, 0, stream>>>(W_qkv, Wqt, 3072);
  gemm_bt<<<dim3(32, 24), gblk, 0, stream>>>(Xb, Wqt, b_qkv, Qw, Kw, Vw, nullptr, 0);
  attn_kernel<<<dim3(1024), blk, 0, stream>>>(Qw, Kw, Vw, AO);
  transpose_w<<<dim3(32, 32), blk, 0, stream>>>(W_out, Wot, 1024);
  gemm_bt<<<dim3(32, 8), gblk, 0, stream>>>(AO, Wot, b_out, nullptr, nullptr, nullptr, out, 1);
}